// Round 15
// baseline (276.441 us; speedup 1.0000x reference)
//
#include <hip/hip_runtime.h>
#include <math.h>

// GeoAB: conv3x3(192->384, bf16 MFMA, counted-vmcnt pipeline) -> [win+row attn | col attn]
//        -> conv3x3(192->192, CT=2, split-K atomic).  B=2, H=W=160, WS=5, NH=8, CPH=8.

typedef __attribute__((ext_vector_type(8))) short short8;
typedef __attribute__((ext_vector_type(4))) short short4v;
typedef __attribute__((ext_vector_type(4))) float f32x4;

constexpr int Hc = 160, Wc = 160, Bc = 2;
constexpr int HPR = 162;   // padded rows
constexpr int HPW = 164;   // padded cols

__device__ inline unsigned short f2bf(float f) {
  union { float f; unsigned u; } v; v.f = f;
  unsigned r = v.u + 0x7FFF + ((v.u >> 16) & 1);
  return (unsigned short)(r >> 16);
}
__device__ inline float bf2f(unsigned short h) {
  union { unsigned u; float f; } v; v.u = ((unsigned)h) << 16;
  return v.f;
}

__device__ inline void gl16(const void* g, void* l) {
  __builtin_amdgcn_global_load_lds((const __attribute__((address_space(1))) unsigned int*)g,
                                   (__attribute__((address_space(3))) unsigned int*)l, 16, 0, 0);
}

__device__ inline float dot8(f32x4 a0, f32x4 a1, f32x4 b0, f32x4 b1) {
  float d = a0[0] * b0[0];
  d = fmaf(a0[1], b0[1], d); d = fmaf(a0[2], b0[2], d); d = fmaf(a0[3], b0[3], d);
  d = fmaf(a1[0], b1[0], d); d = fmaf(a1[1], b1[1], d);
  d = fmaf(a1[2], b1[2], d); d = fmaf(a1[3], b1[3], d);
  return d;
}

// ================= fused prep: nchw->nhwc pad | borders | wxform x2 | cpb | zero-out =================
// frag layout for weights: wtr[(((tap*6+cs)*NT + cotile)*64 + kh*16 + cor)*8 + j]
__global__ __launch_bounds__(256)
void prep_kernel(const float* __restrict__ x, unsigned short* __restrict__ xpad,
                 unsigned short* __restrict__ ypad,
                 const float* __restrict__ w_in, unsigned short* __restrict__ wtr1,
                 const float* __restrict__ w_out, unsigned short* __restrict__ wtr2,
                 const float* __restrict__ cw1, const float* __restrict__ cb1,
                 const float* __restrict__ cw2, float* __restrict__ biasf,
                 float* __restrict__ outz) {
  __shared__ float tile[192][33];
  const int bid = blockIdx.x;
  const int t = threadIdx.x;
  if (bid < 1600) {
    int blk = bid;
    const int w0 = (blk % 5) * 32; blk /= 5;
    const int h = blk % 160;
    const int b = blk / 160;
    for (int i = t; i < 192 * 32; i += 256) {
      int c = i >> 5, w = i & 31;
      tile[c][w] = x[(((size_t)b * 192 + c) * 160 + h) * 160 + w0 + w];
    }
    __syncthreads();
    for (int i = t; i < 32 * 24; i += 256) {
      int w = i / 24, c8 = i % 24;
      short8 o;
#pragma unroll
      for (int k = 0; k < 8; ++k) o[k] = (short)f2bf(tile[c8 * 8 + k][w]);
      *(short8*)(xpad + (((size_t)b * HPR + h + 1) * HPW + w0 + w + 1) * 192 + c8 * 8) = o;
    }
  } else if (bid < 1963) {
    const int NPOS = 968;
    const int total = 2 * 2 * NPOS * 24;
    int idx = (bid - 1600) * 256 + t;
    if (idx >= total) return;
    const int ch = idx % 24; int q = idx / 24;
    const int pos = q % NPOS; q /= NPOS;
    const int b = q & 1; const int buf = q >> 1;
    int row, col;
    if (pos < 328) { row = (pos < 164) ? 0 : 161; col = pos % 164; }
    else { int r = pos - 328; row = 1 + (r >> 2); int cm = r & 3; col = cm == 0 ? 0 : 160 + cm; }
    unsigned short* p = (buf ? ypad : xpad) + (((size_t)b * HPR + row) * HPW + col) * 192 + ch * 8;
    short8 z = {};
    *(short8*)p = z;
  } else if (bid < 2395) {
    const bool first = bid < 2251;
    const int CO = first ? 384 : 192;
    const int NT = CO / 16;
    const float* w = first ? w_in : w_out;
    unsigned short* wtr = first ? wtr1 : wtr2;
    int id = (bid - (first ? 1963 : 2251)) * 256 + t;
    if (id >= CO * 192) return;
    const int co = id / 192, ci = id % 192;
    const int cs = ci >> 5, kh = (ci >> 3) & 3, j = ci & 7;
    const int cotile = co >> 4, cor = co & 15;
    const float* wp = w + (size_t)id * 9;
#pragma unroll
    for (int tap = 0; tap < 9; ++tap)
      wtr[((((size_t)tap * 6 + cs) * NT + cotile) * 64 + kh * 16 + cor) * 8 + j] = f2bf(wp[tap]);
  } else if (bid < 2476) {
    if (t >= 64) return;
    const int e = bid - 2395;
    const int d0 = e / 9, d1 = e % 9;
    const int r0 = d0 - 4, r1 = d1 - 4;
    float t0 = log2f(fabsf((float)r0) * 2.0f + 1.0f) * (1.0f / 3.0f); if (r0 < 0) t0 = -t0;
    float t1 = log2f(fabsf((float)r1) * 2.0f + 1.0f) * (1.0f / 3.0f); if (r1 < 0) t1 = -t1;
    const int lane = t;
    float acc[8];
#pragma unroll
    for (int n = 0; n < 8; ++n) acc[n] = 0.f;
    for (int k = lane; k < 512; k += 64) {
      float hk = fmaf(t0, cw1[k * 2 + 0], fmaf(t1, cw1[k * 2 + 1], cb1[k]));
      hk = fmaxf(hk, 0.f);
#pragma unroll
      for (int n = 0; n < 8; ++n) acc[n] = fmaf(hk, cw2[n * 512 + k], acc[n]);
    }
#pragma unroll
    for (int n = 0; n < 8; ++n) {
#pragma unroll
      for (int off = 32; off > 0; off >>= 1) acc[n] += __shfl_xor(acc[n], off, 64);
    }
    if (lane == 0) {
#pragma unroll
      for (int n = 0; n < 8; ++n)
        biasf[e * 8 + n] = 16.0f / (1.0f + expf(-acc[n]));
    }
  } else {
    // ---- zero the fp32 output (for conv_out split-K atomics): 9,830,400 floats ----
    const long chunk = (long)(bid - 2476) * 256 + t;   // 16B chunks
    if (chunk < 2457600) {
      f32x4 z = {0.f, 0.f, 0.f, 0.f};
      *(f32x4*)(outz + chunk * 4) = z;
    }
  }
}

// ================= conv3x3 SAME, implicit GEMM, counted-vmcnt pipeline =================
// Block: 4 waves, one h-row each; wave tile 80w x (CT*16)co (acc 5xCT). BH=4, slab R=6, dbuf.
// Per cs: stage(next) -> [GROUP(Ak); LOADA(Ak,next)] x3 -> vmcnt(9*CT)+barrier.
// OUTMODE 0 (CT=4): cog 0..3 -> xq NHWC [b][h][w][256]; cog 4 -> xk2k; cog 5 -> xk2v.
// OUTMODE 1: fp32 NCHW store.  OUTMODE 2: split-K (blockIdx.z = b*2+half, 3 cs each),
//            epilogue atomicAdd into pre-zeroed out (2 commutative adds -> deterministic).
template<int COUT, int CT, int OUTMODE>
__global__ __launch_bounds__(256, 2)
void conv_mfma(const unsigned short* __restrict__ xin, const unsigned short* __restrict__ wtrA,
               const float* __restrict__ bias, unsigned short* __restrict__ obf,
               unsigned short* __restrict__ xk2k, unsigned short* __restrict__ xk2v,
               float* __restrict__ of32) {
  constexpr int CIN = 192;
  constexpr int R = 6;
  constexpr int TOTAL = R * 84 * 4;          // 2016 16B chunks per slab
  constexpr int SLAB = R * 84 * 32;          // shorts per buffer
  constexpr int NT = COUT / 16;
  __shared__ unsigned short slab[2 * SLAB];
  const int t = threadIdx.x, lane = t & 63, wid = t >> 6;
  const int bx = blockIdx.x, cog = blockIdx.y;
  const int zz = blockIdx.z;
  const int b    = (OUTMODE == 2) ? (zz >> 1) : zz;
  const int half = (OUTMODE == 2) ? (zz & 1) : 0;
  const int cs0  = half * 3;
  const int ws = bx & 1, hb = bx >> 1;
  const int w0 = ws * 80, h0 = hb * 4;
  const int hr = wid;
  const int l15 = lane & 15, l4 = lane >> 4;
  const int co0 = cog * (CT * 16);

  f32x4 acc[5][CT];
#pragma unroll
  for (int ct = 0; ct < CT; ++ct) {
    f32x4 bi;
#pragma unroll
    for (int r = 0; r < 4; ++r)
      bi[r] = (OUTMODE == 2 && half != 0) ? 0.f : bias[co0 + ct * 16 + l4 * 4 + r];
#pragma unroll
    for (int mt = 0; mt < 5; ++mt) acc[mt][ct] = bi;
  }

  auto stage = [&](int cs, int bufbase) {
#pragma unroll
    for (int ib0 = 0; ib0 < 8; ++ib0) {
      const int ib = ib0 * 4 + wid;
      const int n = ib * 64 + lane;
      if (n < TOTAL) {
        const int c = n & 3, q = n >> 2;
        const int r = q / 84, wv = q - r * 84;
        const int csrc = c ^ ((wv >> 1) & 3);
        const unsigned short* g = xin +
            (((size_t)b * HPR + h0 + r) * HPW + w0 + wv) * CIN + cs * 32 + csrc * 8;
        gl16(g, &slab[bufbase + ib * 512]);
      }
    }
  };

#define BARRIER_CNT                                                              \
  {                                                                              \
    if constexpr (CT == 4)                                                       \
      asm volatile("s_waitcnt vmcnt(36)\n\ts_barrier" ::: "memory");             \
    else                                                                         \
      asm volatile("s_waitcnt vmcnt(18)\n\ts_barrier" ::: "memory");             \
  }

// load 3*CT A-frags (one ky group) into register array a
#define LOADA(a, ky, cs)                                                         \
  {                                                                              \
    _Pragma("unroll")                                                            \
    for (int kx = 0; kx < 3; ++kx) {                                             \
      _Pragma("unroll")                                                          \
      for (int ct = 0; ct < CT; ++ct)                                            \
        a[kx * CT + ct] = *(const short8*)(wtrA +                                \
            ((size_t)(((ky) * 3 + kx) * 6 + (cs)) * NT + cog * CT + ct) * 512 +  \
            lane * 8);                                                           \
    }                                                                            \
  }

// 15*CT MFMAs of one ky group against slab buffer at bufbase
#define GROUP(a, ky, bufbase)                                                    \
  {                                                                              \
    const unsigned short* srow = &slab[(bufbase) + (hr + (ky)) * 84 * 32];       \
    _Pragma("unroll")                                                            \
    for (int kx = 0; kx < 3; ++kx) {                                             \
      _Pragma("unroll")                                                          \
      for (int mt = 0; mt < 5; ++mt) {                                           \
        const int wv = mt * 16 + l15 + kx;                                       \
        const int cr = l4 ^ ((wv >> 1) & 3);                                     \
        short8 bf = *(const short8*)(srow + wv * 32 + cr * 8);                   \
        _Pragma("unroll")                                                        \
        for (int ct = 0; ct < CT; ++ct)                                          \
          acc[mt][ct] =                                                          \
              __builtin_amdgcn_mfma_f32_16x16x32_bf16(a[kx * CT + ct], bf,       \
                                                      acc[mt][ct], 0, 0, 0);     \
      }                                                                          \
    }                                                                            \
  }

// one cs step; A0f/A1f/A2f hold cs's fragments on entry, cs+1's on exit
#define CSBODY(cs, base, nbase, LAST)                                            \
  {                                                                              \
    if (!(LAST)) stage((cs) + 1, nbase);                                         \
    __builtin_amdgcn_s_setprio(1);                                               \
    GROUP(A0f, 0, base);                                                         \
    __builtin_amdgcn_s_setprio(0);                                               \
    if (!(LAST)) LOADA(A0f, 0, (cs) + 1);                                        \
    __builtin_amdgcn_s_setprio(1);                                               \
    GROUP(A1f, 1, base);                                                         \
    __builtin_amdgcn_s_setprio(0);                                               \
    if (!(LAST)) LOADA(A1f, 1, (cs) + 1);                                        \
    __builtin_amdgcn_s_setprio(1);                                               \
    GROUP(A2f, 2, base);                                                         \
    __builtin_amdgcn_s_setprio(0);                                               \
    if (!(LAST)) {                                                               \
      LOADA(A2f, 2, (cs) + 1);                                                   \
      BARRIER_CNT;                                                               \
    }                                                                            \
  }

  short8 A0f[3 * CT], A1f[3 * CT], A2f[3 * CT];
  stage(cs0, 0);
  LOADA(A0f, 0, cs0);
  LOADA(A1f, 1, cs0);
  LOADA(A2f, 2, cs0);
  BARRIER_CNT;

  if constexpr (OUTMODE == 2) {
    CSBODY(cs0 + 0, 0, SLAB, 0);
    CSBODY(cs0 + 1, SLAB, 0, 0);
    CSBODY(cs0 + 2, 0, SLAB, 1);
  } else {
    CSBODY(0, 0, SLAB, 0);
    CSBODY(1, SLAB, 0, 0);
    CSBODY(2, 0, SLAB, 0);
    CSBODY(3, SLAB, 0, 0);
    CSBODY(4, 0, SLAB, 0);
    CSBODY(5, SLAB, 0, 1);
  }
#undef LOADA
#undef GROUP
#undef CSBODY
#undef BARRIER_CNT

  // ---- epilogue: D row = co (l4*4+r), col = w (l15) ----
  const int h = h0 + hr;
  if (OUTMODE == 0) {
    if (co0 < 256) {
#pragma unroll
      for (int mt = 0; mt < 5; ++mt) {
        const int w = w0 + mt * 16 + l15;
        unsigned short* dst0 = obf + (((size_t)b * Hc + h) * Wc + w) * 256 + co0 + l4 * 4;
#pragma unroll
        for (int ct = 0; ct < CT; ++ct) {
          short4v s;
#pragma unroll
          for (int r = 0; r < 4; ++r) s[r] = (short)f2bf(acc[mt][ct][r]);
          *(short4v*)(dst0 + ct * 16) = s;
        }
      }
    } else {
      unsigned short* xk2 = (co0 == 256) ? xk2k : xk2v;
#pragma unroll
      for (int mt = 0; mt < 5; ++mt) {
        const int w = w0 + mt * 16 + l15;
#pragma unroll
        for (int ct = 0; ct < CT; ++ct) {
          const int rel = ct * 16 + l4 * 4;
          const int head = rel >> 3, within = rel & 7;
          short4v s;
#pragma unroll
          for (int r = 0; r < 4; ++r) s[r] = (short)f2bf(acc[mt][ct][r]);
          *(short4v*)(xk2 + ((((size_t)b * 8 + head) * 160 + h) * 160 + w) * 8 + within) = s;
        }
      }
    }
  } else if (OUTMODE == 1) {
#pragma unroll
    for (int mt = 0; mt < 5; ++mt) {
      const int w = w0 + mt * 16 + l15;
#pragma unroll
      for (int ct = 0; ct < CT; ++ct)
#pragma unroll
        for (int r = 0; r < 4; ++r) {
          const int co = co0 + ct * 16 + l4 * 4 + r;
          of32[(((size_t)b * COUT + co) * Hc + h) * Wc + w] = acc[mt][ct][r];
        }
    }
  } else {
#pragma unroll
    for (int mt = 0; mt < 5; ++mt) {
      const int w = w0 + mt * 16 + l15;
#pragma unroll
      for (int ct = 0; ct < CT; ++ct)
#pragma unroll
        for (int r = 0; r < 4; ++r) {
          const int co = co0 + ct * 16 + l4 * 4 + r;
          atomicAdd(&of32[(((size_t)b * COUT + co) * Hc + h) * Wc + w], acc[mt][ct][r]);
        }
    }
  }
}

// ================= fused attn pass 1: window attn (both variants) + axial row pass =================
__global__ __launch_bounds__(256)
void attn1_kernel(const unsigned short* __restrict__ xq, const float* __restrict__ biasf,
                  const float* __restrict__ logit_scale, const float* __restrict__ lrs,
                  const unsigned short* __restrict__ xk2k, const unsigned short* __restrict__ xk2v,
                  unsigned short* __restrict__ ypad, unsigned short* __restrict__ vrow) {
  const int bid = blockIdx.x;
  if (bid < 4096) {
    // ---- 5x5 window cosine attention ----
    __shared__ f32x4 kn4[8][25][2];
    __shared__ f32x4 vv4[8][25][2];
    const int t = threadIdx.x;
    const int head = t & 7;
    const int i = t >> 3;           // 0..31, active < 25
    const int b = bid >> 11;
    const int r = bid & 2047;
    const int variant = r >> 10;
    const int blk = r & 1023;
    const int chan_off = variant ? 128 : 0;
    const int y_ch_off = variant ? 64 : 0;
    const int shift_in = variant ? 3 : 0;
    const int shift_out = variant ? 2 : 0;
    const int wb_i = blk % 32, hb_i = blk / 32;
    const int wi = i / 5, wj = i % 5;
    const int gh = hb_i * 5 + wi, gw = wb_i * 5 + wj;
    const int sh = (gh + shift_in) % Hc, sw = (gw + shift_in) % Wc;

    if (i < 25) {
      const unsigned short* base = xq + (((size_t)b * Hc + sh) * Wc + sw) * 256 + chan_off + head * 8;
      short8 kv = *(const short8*)base;
      short8 vv = *(const short8*)(base + 64);
      float k[8]; float nrm = 0.f;
#pragma unroll
      for (int c = 0; c < 8; ++c) { k[c] = bf2f((unsigned short)kv[c]); nrm = fmaf(k[c], k[c], nrm); }
      const float inv = 1.0f / fmaxf(sqrtf(nrm), 1e-12f);
      f32x4 a0, a1, b0, b1;
#pragma unroll
      for (int c = 0; c < 4; ++c) { a0[c] = k[c] * inv; a1[c] = k[c + 4] * inv; }
#pragma unroll
      for (int c = 0; c < 4; ++c) { b0[c] = bf2f((unsigned short)vv[c]); b1[c] = bf2f((unsigned short)vv[c + 4]); }
      kn4[head][i][0] = a0; kn4[head][i][1] = a1;
      vv4[head][i][0] = b0; vv4[head][i][1] = b1;
    }
    __syncthreads();
    if (i >= 25) return;

    const float scale = expf(fminf(logit_scale[head], 4.6051702f));
    const f32x4 q0 = kn4[head][i][0], q1 = kn4[head][i][1];
    float s[25];
#pragma unroll
    for (int j = 0; j < 25; ++j) {
      const float d = dot8(q0, q1, kn4[head][j][0], kn4[head][j][1]);
      const int d0 = wi - (j / 5) + 4, d1 = wj - (j % 5) + 4;
      s[j] = fmaf(d, scale, biasf[(d0 * 9 + d1) * 8 + head]);
    }
    float m = -1e30f;
#pragma unroll
    for (int j = 0; j < 25; ++j) m = fmaxf(m, s[j]);
    float den = 0.f;
    f32x4 acc0 = {0.f, 0.f, 0.f, 0.f}, acc1 = {0.f, 0.f, 0.f, 0.f};
#pragma unroll
    for (int j = 0; j < 25; ++j) {
      const float p = __expf(s[j] - m);
      den += p;
      acc0 += vv4[head][j][0] * p;
      acc1 += vv4[head][j][1] * p;
    }
    const float rden = 1.0f / den;
    const int oh = (gh + shift_out) % Hc, ow = (gw + shift_out) % Wc;
    short8 o;
#pragma unroll
    for (int c = 0; c < 4; ++c) { o[c] = (short)f2bf(acc0[c] * rden); o[c + 4] = (short)f2bf(acc1[c] * rden); }
    *(short8*)(ypad + (((size_t)b * HPR + oh + 1) * HPW + ow + 1) * 192 + y_ch_off + head * 8) = o;
  } else {
    // ---- axial row pass -> vrow bf16 [b][head][h][w][8] ----
    __shared__ f32x4 kn4[160][2];
    __shared__ f32x4 vv4[160][2];
    int u = bid - 4096;
    const int head = u % 8; u /= 8;
    const int h = u % 160;
    const int b = u / 160;
    const int i = threadIdx.x;

    if (i < 160) {
      const size_t base = ((((size_t)b * 8 + head) * 160 + h) * 160 + i) * 8;
      short8 kv = *(const short8*)(xk2k + base);
      short8 vv = *(const short8*)(xk2v + base);
      float k[8]; float nrm = 0.f;
#pragma unroll
      for (int c = 0; c < 8; ++c) { k[c] = bf2f((unsigned short)kv[c]); nrm = fmaf(k[c], k[c], nrm); }
      const float inv = 1.0f / fmaxf(sqrtf(nrm), 1e-12f);
      f32x4 a0, a1, b0, b1;
#pragma unroll
      for (int c = 0; c < 4; ++c) { a0[c] = k[c] * inv; a1[c] = k[c + 4] * inv; }
#pragma unroll
      for (int c = 0; c < 4; ++c) { b0[c] = bf2f((unsigned short)vv[c]); b1[c] = bf2f((unsigned short)vv[c + 4]); }
      kn4[i][0] = a0; kn4[i][1] = a1;
      vv4[i][0] = b0; vv4[i][1] = b1;
    }
    __syncthreads();
    if (i >= 160) return;

    const float scale = expf(fminf(lrs[head], 4.6051702f));
    const f32x4 q0 = kn4[i][0], q1 = kn4[i][1];
    float den = 0.f;
    f32x4 acc0 = {0.f, 0.f, 0.f, 0.f}, acc1 = {0.f, 0.f, 0.f, 0.f};
    for (int j = 0; j < 160; ++j) {
      const float d = dot8(q0, q1, kn4[j][0], kn4[j][1]);
      const float p = __expf(fmaf(d, scale, -scale));
      den += p;
      acc0 += vv4[j][0] * p;
      acc1 += vv4[j][1] * p;
    }
    const float rden = 1.0f / den;
    short8 o;
#pragma unroll
    for (int c = 0; c < 4; ++c) { o[c] = (short)f2bf(acc0[c] * rden); o[c + 4] = (short)f2bf(acc1[c] * rden); }
    *(short8*)(vrow + ((((size_t)b * 8 + head) * 160 + h) * 160 + i) * 8) = o;
  }
}

// ================= axial column pass: block = (b, head, 4-col group), 640 threads =================
__global__ __launch_bounds__(640)
void col_attn_kernel(const unsigned short* __restrict__ xk2k, const float* __restrict__ lrs,
                     const unsigned short* __restrict__ vrow, unsigned short* __restrict__ ypad) {
  __shared__ f32x4 knT[4][161][2];
  __shared__ f32x4 vvT[4][161][2];
  int blk = blockIdx.x;
  const int wg = blk % 40; blk /= 40;
  const int head = blk % 8;
  const int b = blk / 8;
  const int w0 = wg * 4;
  const int t = threadIdx.x;

  {
    const int h = t >> 2, wc = t & 3;
    const size_t base = ((((size_t)b * 8 + head) * 160 + h) * 160 + (w0 + wc)) * 8;
    short8 kv = *(const short8*)(xk2k + base);
    short8 vv = *(const short8*)(vrow + base);
    float k[8]; float nrm = 0.f;
#pragma unroll
    for (int c = 0; c < 8; ++c) { k[c] = bf2f((unsigned short)kv[c]); nrm = fmaf(k[c], k[c], nrm); }
    const float inv = 1.0f / fmaxf(sqrtf(nrm), 1e-12f);
    f32x4 a0, a1, b0, b1;
#pragma unroll
    for (int c = 0; c < 4; ++c) { a0[c] = k[c] * inv; a1[c] = k[c + 4] * inv; }
#pragma unroll
    for (int c = 0; c < 4; ++c) { b0[c] = bf2f((unsigned short)vv[c]); b1[c] = bf2f((unsigned short)vv[c + 4]); }
    knT[wc][h][0] = a0; knT[wc][h][1] = a1;
    vvT[wc][h][0] = b0; vvT[wc][h][1] = b1;
  }
  __syncthreads();

  const int wi = t / 160, i = t % 160;
  const float scale = expf(fminf(lrs[head], 4.6051702f));
  const f32x4 q0 = knT[wi][i][0], q1 = knT[wi][i][1];
  float den = 0.f;
  f32x4 acc0 = {0.f, 0.f, 0.f, 0.f}, acc1 = {0.f, 0.f, 0.f, 0.f};
  for (int j = 0; j < 160; ++j) {
    const float d = dot8(q0, q1, knT[wi][j][0], knT[wi][j][1]);
    const float p = __expf(fmaf(d, scale, -scale));
    den += p;
    acc0 += vvT[wi][j][0] * p;
    acc1 += vvT[wi][j][1] * p;
  }
  const float rden = 1.0f / den;
  short8 o;
#pragma unroll
  for (int c = 0; c < 4; ++c) { o[c] = (short)f2bf(acc0[c] * rden); o[c + 4] = (short)f2bf(acc1[c] * rden); }
  *(short8*)(ypad + (((size_t)b * HPR + i + 1) * HPW + w0 + wi + 1) * 192 + 128 + head * 8) = o;
}

extern "C" void kernel_launch(void* const* d_in, const int* in_sizes, int n_in,
                              void* d_out, int out_size, void* d_ws, size_t ws_size,
                              hipStream_t stream) {
  const float* x     = (const float*)d_in[0];
  const float* w_in  = (const float*)d_in[1];
  const float* b_in  = (const float*)d_in[2];
  const float* w_out = (const float*)d_in[3];
  const float* b_out = (const float*)d_in[4];
  const float* ls    = (const float*)d_in[5];
  const float* lrs   = (const float*)d_in[6];
  const float* cw1   = (const float*)d_in[7];
  const float* cb1   = (const float*)d_in[8];
  const float* cw2   = (const float*)d_in[9];
  float* out = (float*)d_out;

  // workspace layout
  char* p = (char*)d_ws;
  unsigned short* xpad = (unsigned short*)p;  p += (size_t)Bc * HPR * HPW * 192 * 2;   // 20.4 MB
  unsigned short* ypad = (unsigned short*)p;  p += (size_t)Bc * HPR * HPW * 192 * 2;   // 20.4 MB
  unsigned short* xq   = (unsigned short*)p;  p += (size_t)Bc * Hc * Wc * 256 * 2;     // 26.2 MB
  unsigned short* xk2k = (unsigned short*)p;  p += (size_t)Bc * 8 * Hc * Wc * 8 * 2;   //  6.6 MB
  unsigned short* xk2v = (unsigned short*)p;  p += (size_t)Bc * 8 * Hc * Wc * 8 * 2;   //  6.6 MB
  unsigned short* vrow = (unsigned short*)p;  p += (size_t)Bc * 8 * Hc * Wc * 8 * 2;   //  6.6 MB
  unsigned short* wtr1 = (unsigned short*)p;  p += (size_t)9 * 384 * 192 * 2;          //  1.3 MB
  unsigned short* wtr2 = (unsigned short*)p;  p += (size_t)9 * 192 * 192 * 2;          //  0.7 MB
  float* biasf = (float*)p;

  // 1) fused prep (incl. zero of out for split-K atomics): 2476 + 9600 blocks
  prep_kernel<<<12076, 256, 0, stream>>>(x, xpad, ypad, w_in, wtr1, w_out, wtr2,
                                         cw1, cb1, cw2, biasf, out);
  // 2) conv_in 192->384, CT=4 (xq + xk2k/xk2v epilogue), 960 blocks
  conv_mfma<384, 4, 0><<<dim3(80, 6, Bc), 256, 0, stream>>>(xpad, wtr1, b_in, xq, xk2k, xk2v, nullptr);
  // 3) window attn (both variants) + axial row pass
  attn1_kernel<<<4096 + Bc * 160 * 8, 256, 0, stream>>>(xq, biasf, ls, lrs, xk2k, xk2v, ypad, vrow);
  // 4) axial column pass
  col_attn_kernel<<<Bc * 8 * 40, 640, 0, stream>>>(xk2k, lrs, vrow, ypad);
  // 5) conv_out 192->192, CT=2, split-K (z = b*2+half): 1920 blocks, 3 cs each, atomicAdd
  conv_mfma<192, 2, 2><<<dim3(80, 6, Bc * 2), 256, 0, stream>>>(ypad, wtr2, b_out, nullptr, nullptr, nullptr, out);
}

// Round 16
// 246.751 us; speedup vs baseline: 1.1203x; 1.1203x over previous
//
#include <hip/hip_runtime.h>
#include <math.h>

// GeoAB: conv3x3(192->384, bf16 MFMA, counted-vmcnt, 8-wave blocks) -> [win+row attn | col attn]
//        -> conv3x3(192->192, 8-wave).  B=2, H=W=160, WS=5, NH=8, CPH=8.

typedef __attribute__((ext_vector_type(8))) short short8;
typedef __attribute__((ext_vector_type(4))) short short4v;
typedef __attribute__((ext_vector_type(4))) float f32x4;

constexpr int Hc = 160, Wc = 160, Bc = 2;
constexpr int HPR = 162;   // padded rows
constexpr int HPW = 164;   // padded cols

__device__ inline unsigned short f2bf(float f) {
  union { float f; unsigned u; } v; v.f = f;
  unsigned r = v.u + 0x7FFF + ((v.u >> 16) & 1);
  return (unsigned short)(r >> 16);
}
__device__ inline float bf2f(unsigned short h) {
  union { unsigned u; float f; } v; v.u = ((unsigned)h) << 16;
  return v.f;
}

__device__ inline void gl16(const void* g, void* l) {
  __builtin_amdgcn_global_load_lds((const __attribute__((address_space(1))) unsigned int*)g,
                                   (__attribute__((address_space(3))) unsigned int*)l, 16, 0, 0);
}

__device__ inline float dot8(f32x4 a0, f32x4 a1, f32x4 b0, f32x4 b1) {
  float d = a0[0] * b0[0];
  d = fmaf(a0[1], b0[1], d); d = fmaf(a0[2], b0[2], d); d = fmaf(a0[3], b0[3], d);
  d = fmaf(a1[0], b1[0], d); d = fmaf(a1[1], b1[1], d);
  d = fmaf(a1[2], b1[2], d); d = fmaf(a1[3], b1[3], d);
  return d;
}

// ================= fused prep: nchw->nhwc pad | borders | wxform x2 | cpb =================
// frag layout for weights: wtr[(((tap*6+cs)*NT + cotile)*64 + kh*16 + cor)*8 + j]
__global__ __launch_bounds__(256)
void prep_kernel(const float* __restrict__ x, unsigned short* __restrict__ xpad,
                 unsigned short* __restrict__ ypad,
                 const float* __restrict__ w_in, unsigned short* __restrict__ wtr1,
                 const float* __restrict__ w_out, unsigned short* __restrict__ wtr2,
                 const float* __restrict__ cw1, const float* __restrict__ cb1,
                 const float* __restrict__ cw2, float* __restrict__ biasf) {
  __shared__ float tile[192][33];
  const int bid = blockIdx.x;
  const int t = threadIdx.x;
  if (bid < 1600) {
    int blk = bid;
    const int w0 = (blk % 5) * 32; blk /= 5;
    const int h = blk % 160;
    const int b = blk / 160;
    for (int i = t; i < 192 * 32; i += 256) {
      int c = i >> 5, w = i & 31;
      tile[c][w] = x[(((size_t)b * 192 + c) * 160 + h) * 160 + w0 + w];
    }
    __syncthreads();
    for (int i = t; i < 32 * 24; i += 256) {
      int w = i / 24, c8 = i % 24;
      short8 o;
#pragma unroll
      for (int k = 0; k < 8; ++k) o[k] = (short)f2bf(tile[c8 * 8 + k][w]);
      *(short8*)(xpad + (((size_t)b * HPR + h + 1) * HPW + w0 + w + 1) * 192 + c8 * 8) = o;
    }
  } else if (bid < 1963) {
    const int NPOS = 968;
    const int total = 2 * 2 * NPOS * 24;
    int idx = (bid - 1600) * 256 + t;
    if (idx >= total) return;
    const int ch = idx % 24; int q = idx / 24;
    const int pos = q % NPOS; q /= NPOS;
    const int b = q & 1; const int buf = q >> 1;
    int row, col;
    if (pos < 328) { row = (pos < 164) ? 0 : 161; col = pos % 164; }
    else { int r = pos - 328; row = 1 + (r >> 2); int cm = r & 3; col = cm == 0 ? 0 : 160 + cm; }
    unsigned short* p = (buf ? ypad : xpad) + (((size_t)b * HPR + row) * HPW + col) * 192 + ch * 8;
    short8 z = {};
    *(short8*)p = z;
  } else if (bid < 2395) {
    const bool first = bid < 2251;
    const int CO = first ? 384 : 192;
    const int NT = CO / 16;
    const float* w = first ? w_in : w_out;
    unsigned short* wtr = first ? wtr1 : wtr2;
    int id = (bid - (first ? 1963 : 2251)) * 256 + t;
    if (id >= CO * 192) return;
    const int co = id / 192, ci = id % 192;
    const int cs = ci >> 5, kh = (ci >> 3) & 3, j = ci & 7;
    const int cotile = co >> 4, cor = co & 15;
    const float* wp = w + (size_t)id * 9;
#pragma unroll
    for (int tap = 0; tap < 9; ++tap)
      wtr[((((size_t)tap * 6 + cs) * NT + cotile) * 64 + kh * 16 + cor) * 8 + j] = f2bf(wp[tap]);
  } else {
    if (t >= 64) return;
    const int e = bid - 2395;
    const int d0 = e / 9, d1 = e % 9;
    const int r0 = d0 - 4, r1 = d1 - 4;
    float t0 = log2f(fabsf((float)r0) * 2.0f + 1.0f) * (1.0f / 3.0f); if (r0 < 0) t0 = -t0;
    float t1 = log2f(fabsf((float)r1) * 2.0f + 1.0f) * (1.0f / 3.0f); if (r1 < 0) t1 = -t1;
    const int lane = t;
    float acc[8];
#pragma unroll
    for (int n = 0; n < 8; ++n) acc[n] = 0.f;
    for (int k = lane; k < 512; k += 64) {
      float hk = fmaf(t0, cw1[k * 2 + 0], fmaf(t1, cw1[k * 2 + 1], cb1[k]));
      hk = fmaxf(hk, 0.f);
#pragma unroll
      for (int n = 0; n < 8; ++n) acc[n] = fmaf(hk, cw2[n * 512 + k], acc[n]);
    }
#pragma unroll
    for (int n = 0; n < 8; ++n) {
#pragma unroll
      for (int off = 32; off > 0; off >>= 1) acc[n] += __shfl_xor(acc[n], off, 64);
    }
    if (lane == 0) {
#pragma unroll
      for (int n = 0; n < 8; ++n)
        biasf[e * 8 + n] = 16.0f / (1.0f + expf(-acc[n]));
    }
  }
}

// ================= conv3x3 SAME, implicit GEMM, counted-vmcnt pipeline =================
// Block: WAVES = 4*NWH waves, wid -> (hr = wid/NWH h-row, wh = wid%NWH co-half).
// Wave tile 80w x (CT*16)co (acc 5xCT). Block co-range = CT*16*NWH. BH=4, slab R=6, dbuf.
// Per cs: stage(next) -> [GROUP(Ak); LOADA(Ak,next)] x3 -> vmcnt(9*CT)+barrier
// (drains own-wave gl16s, keeps A-loads in flight).
// OUTMODE 0: co<256 -> xq NHWC [b][h][w][256]; 256.. -> xk2k/xk2v head-major.
// OUTMODE 1: fp32 NCHW store.
template<int COUT, int CT, int NWH, int OUTMODE>
__global__ __launch_bounds__(256 * NWH, 4)
void conv_mfma(const unsigned short* __restrict__ xin, const unsigned short* __restrict__ wtrA,
               const float* __restrict__ bias, unsigned short* __restrict__ obf,
               unsigned short* __restrict__ xk2k, unsigned short* __restrict__ xk2v,
               float* __restrict__ of32) {
  constexpr int CIN = 192;
  constexpr int R = 6;
  constexpr int WAVES = 4 * NWH;
  constexpr int TOTAL = R * 84 * 4;          // 2016 16B chunks per slab
  constexpr int SLAB = R * 84 * 32;          // shorts per buffer
  constexpr int NT = COUT / 16;
  constexpr int IB0 = (TOTAL / 64 + WAVES - 1) / WAVES;   // gl16 rounds per wave
  __shared__ unsigned short slab[2 * SLAB];
  const int t = threadIdx.x, lane = t & 63, wid = t >> 6;
  const int bx = blockIdx.x, cog = blockIdx.y, b = blockIdx.z;
  const int ws = bx & 1, hb = bx >> 1;
  const int w0 = ws * 80, h0 = hb * 4;
  const int hr = wid / NWH, wh = wid % NWH;
  const int l15 = lane & 15, l4 = lane >> 4;
  const int co0 = cog * (CT * 16 * NWH) + wh * (CT * 16);

  f32x4 acc[5][CT];
#pragma unroll
  for (int ct = 0; ct < CT; ++ct) {
    f32x4 bi;
#pragma unroll
    for (int r = 0; r < 4; ++r) bi[r] = bias[co0 + ct * 16 + l4 * 4 + r];
#pragma unroll
    for (int mt = 0; mt < 5; ++mt) acc[mt][ct] = bi;
  }

  auto stage = [&](int cs, int bufbase) {
#pragma unroll
    for (int ib0 = 0; ib0 < IB0; ++ib0) {
      const int ib = ib0 * WAVES + wid;
      const int n = ib * 64 + lane;
      if (n < TOTAL) {
        const int c = n & 3, q = n >> 2;
        const int r = q / 84, wv = q - r * 84;
        const int csrc = c ^ ((wv >> 1) & 3);
        const unsigned short* g = xin +
            (((size_t)b * HPR + h0 + r) * HPW + w0 + wv) * CIN + cs * 32 + csrc * 8;
        gl16(g, &slab[bufbase + ib * 512]);
      }
    }
  };

#define BARRIER_CNT                                                              \
  {                                                                              \
    if constexpr (CT == 4)                                                       \
      asm volatile("s_waitcnt vmcnt(36)\n\ts_barrier" ::: "memory");             \
    else                                                                         \
      asm volatile("s_waitcnt vmcnt(18)\n\ts_barrier" ::: "memory");             \
  }

// load 3*CT A-frags (one ky group) into register array a
#define LOADA(a, ky, cs)                                                         \
  {                                                                              \
    _Pragma("unroll")                                                            \
    for (int kx = 0; kx < 3; ++kx) {                                             \
      _Pragma("unroll")                                                          \
      for (int ct = 0; ct < CT; ++ct)                                            \
        a[kx * CT + ct] = *(const short8*)(wtrA +                                \
            ((size_t)(((ky) * 3 + kx) * 6 + (cs)) * NT + cog * (CT * NWH) +      \
             wh * CT + ct) * 512 + lane * 8);                                    \
    }                                                                            \
  }

// 15*CT MFMAs of one ky group against slab buffer at bufbase
#define GROUP(a, ky, bufbase)                                                    \
  {                                                                              \
    const unsigned short* srow = &slab[(bufbase) + (hr + (ky)) * 84 * 32];       \
    _Pragma("unroll")                                                            \
    for (int kx = 0; kx < 3; ++kx) {                                             \
      _Pragma("unroll")                                                          \
      for (int mt = 0; mt < 5; ++mt) {                                           \
        const int wv = mt * 16 + l15 + kx;                                       \
        const int cr = l4 ^ ((wv >> 1) & 3);                                     \
        short8 bf = *(const short8*)(srow + wv * 32 + cr * 8);                   \
        _Pragma("unroll")                                                        \
        for (int ct = 0; ct < CT; ++ct)                                          \
          acc[mt][ct] =                                                          \
              __builtin_amdgcn_mfma_f32_16x16x32_bf16(a[kx * CT + ct], bf,       \
                                                      acc[mt][ct], 0, 0, 0);     \
      }                                                                          \
    }                                                                            \
  }

// one cs step; A0f/A1f/A2f hold cs's fragments on entry, cs+1's on exit
#define CSBODY(cs, base, nbase, LAST)                                            \
  {                                                                              \
    if (!(LAST)) stage((cs) + 1, nbase);                                         \
    __builtin_amdgcn_s_setprio(1);                                               \
    GROUP(A0f, 0, base);                                                         \
    __builtin_amdgcn_s_setprio(0);                                               \
    if (!(LAST)) LOADA(A0f, 0, (cs) + 1);                                        \
    __builtin_amdgcn_s_setprio(1);                                               \
    GROUP(A1f, 1, base);                                                         \
    __builtin_amdgcn_s_setprio(0);                                               \
    if (!(LAST)) LOADA(A1f, 1, (cs) + 1);                                        \
    __builtin_amdgcn_s_setprio(1);                                               \
    GROUP(A2f, 2, base);                                                         \
    __builtin_amdgcn_s_setprio(0);                                               \
    if (!(LAST)) {                                                               \
      LOADA(A2f, 2, (cs) + 1);                                                   \
      BARRIER_CNT;                                                               \
    }                                                                            \
  }

  short8 A0f[3 * CT], A1f[3 * CT], A2f[3 * CT];
  stage(0, 0);
  LOADA(A0f, 0, 0);
  LOADA(A1f, 1, 0);
  LOADA(A2f, 2, 0);
  BARRIER_CNT;

  CSBODY(0, 0, SLAB, 0);
  CSBODY(1, SLAB, 0, 0);
  CSBODY(2, 0, SLAB, 0);
  CSBODY(3, SLAB, 0, 0);
  CSBODY(4, 0, SLAB, 0);
  CSBODY(5, SLAB, 0, 1);
#undef LOADA
#undef GROUP
#undef CSBODY
#undef BARRIER_CNT

  // ---- epilogue: D row = co (l4*4+r), col = w (l15) ----
  const int h = h0 + hr;
  if (OUTMODE == 0) {
    if (co0 < 256) {
#pragma unroll
      for (int mt = 0; mt < 5; ++mt) {
        const int w = w0 + mt * 16 + l15;
        unsigned short* dst0 = obf + (((size_t)b * Hc + h) * Wc + w) * 256 + co0 + l4 * 4;
#pragma unroll
        for (int ct = 0; ct < CT; ++ct) {
          short4v s;
#pragma unroll
          for (int r = 0; r < 4; ++r) s[r] = (short)f2bf(acc[mt][ct][r]);
          *(short4v*)(dst0 + ct * 16) = s;
        }
      }
    } else {
      unsigned short* xk2 = (co0 < 320) ? xk2k : xk2v;
      const int cb = co0 & 63;      // offset within the 64-ch head group
#pragma unroll
      for (int mt = 0; mt < 5; ++mt) {
        const int w = w0 + mt * 16 + l15;
#pragma unroll
        for (int ct = 0; ct < CT; ++ct) {
          const int rel = cb + ct * 16 + l4 * 4;
          const int head = rel >> 3, within = rel & 7;
          short4v s;
#pragma unroll
          for (int r = 0; r < 4; ++r) s[r] = (short)f2bf(acc[mt][ct][r]);
          *(short4v*)(xk2 + ((((size_t)b * 8 + head) * 160 + h) * 160 + w) * 8 + within) = s;
        }
      }
    }
  } else {
#pragma unroll
    for (int mt = 0; mt < 5; ++mt) {
      const int w = w0 + mt * 16 + l15;
#pragma unroll
      for (int ct = 0; ct < CT; ++ct)
#pragma unroll
        for (int r = 0; r < 4; ++r) {
          const int co = co0 + ct * 16 + l4 * 4 + r;
          of32[(((size_t)b * COUT + co) * Hc + h) * Wc + w] = acc[mt][ct][r];
        }
    }
  }
}

// ================= fused attn pass 1: window attn (both variants) + axial row pass =================
__global__ __launch_bounds__(256)
void attn1_kernel(const unsigned short* __restrict__ xq, const float* __restrict__ biasf,
                  const float* __restrict__ logit_scale, const float* __restrict__ lrs,
                  const unsigned short* __restrict__ xk2k, const unsigned short* __restrict__ xk2v,
                  unsigned short* __restrict__ ypad, unsigned short* __restrict__ vrow) {
  const int bid = blockIdx.x;
  if (bid < 4096) {
    // ---- 5x5 window cosine attention ----
    __shared__ f32x4 kn4[8][25][2];
    __shared__ f32x4 vv4[8][25][2];
    const int t = threadIdx.x;
    const int head = t & 7;
    const int i = t >> 3;           // 0..31, active < 25
    const int b = bid >> 11;
    const int r = bid & 2047;
    const int variant = r >> 10;
    const int blk = r & 1023;
    const int chan_off = variant ? 128 : 0;
    const int y_ch_off = variant ? 64 : 0;
    const int shift_in = variant ? 3 : 0;
    const int shift_out = variant ? 2 : 0;
    const int wb_i = blk % 32, hb_i = blk / 32;
    const int wi = i / 5, wj = i % 5;
    const int gh = hb_i * 5 + wi, gw = wb_i * 5 + wj;
    const int sh = (gh + shift_in) % Hc, sw = (gw + shift_in) % Wc;

    if (i < 25) {
      const unsigned short* base = xq + (((size_t)b * Hc + sh) * Wc + sw) * 256 + chan_off + head * 8;
      short8 kv = *(const short8*)base;
      short8 vv = *(const short8*)(base + 64);
      float k[8]; float nrm = 0.f;
#pragma unroll
      for (int c = 0; c < 8; ++c) { k[c] = bf2f((unsigned short)kv[c]); nrm = fmaf(k[c], k[c], nrm); }
      const float inv = 1.0f / fmaxf(sqrtf(nrm), 1e-12f);
      f32x4 a0, a1, b0, b1;
#pragma unroll
      for (int c = 0; c < 4; ++c) { a0[c] = k[c] * inv; a1[c] = k[c + 4] * inv; }
#pragma unroll
      for (int c = 0; c < 4; ++c) { b0[c] = bf2f((unsigned short)vv[c]); b1[c] = bf2f((unsigned short)vv[c + 4]); }
      kn4[head][i][0] = a0; kn4[head][i][1] = a1;
      vv4[head][i][0] = b0; vv4[head][i][1] = b1;
    }
    __syncthreads();
    if (i >= 25) return;

    const float scale = expf(fminf(logit_scale[head], 4.6051702f));
    const f32x4 q0 = kn4[head][i][0], q1 = kn4[head][i][1];
    float s[25];
#pragma unroll
    for (int j = 0; j < 25; ++j) {
      const float d = dot8(q0, q1, kn4[head][j][0], kn4[head][j][1]);
      const int d0 = wi - (j / 5) + 4, d1 = wj - (j % 5) + 4;
      s[j] = fmaf(d, scale, biasf[(d0 * 9 + d1) * 8 + head]);
    }
    float m = -1e30f;
#pragma unroll
    for (int j = 0; j < 25; ++j) m = fmaxf(m, s[j]);
    float den = 0.f;
    f32x4 acc0 = {0.f, 0.f, 0.f, 0.f}, acc1 = {0.f, 0.f, 0.f, 0.f};
#pragma unroll
    for (int j = 0; j < 25; ++j) {
      const float p = __expf(s[j] - m);
      den += p;
      acc0 += vv4[head][j][0] * p;
      acc1 += vv4[head][j][1] * p;
    }
    const float rden = 1.0f / den;
    const int oh = (gh + shift_out) % Hc, ow = (gw + shift_out) % Wc;
    short8 o;
#pragma unroll
    for (int c = 0; c < 4; ++c) { o[c] = (short)f2bf(acc0[c] * rden); o[c + 4] = (short)f2bf(acc1[c] * rden); }
    *(short8*)(ypad + (((size_t)b * HPR + oh + 1) * HPW + ow + 1) * 192 + y_ch_off + head * 8) = o;
  } else {
    // ---- axial row pass -> vrow bf16 [b][head][h][w][8] ----
    __shared__ f32x4 kn4[160][2];
    __shared__ f32x4 vv4[160][2];
    int u = bid - 4096;
    const int head = u % 8; u /= 8;
    const int h = u % 160;
    const int b = u / 160;
    const int i = threadIdx.x;

    if (i < 160) {
      const size_t base = ((((size_t)b * 8 + head) * 160 + h) * 160 + i) * 8;
      short8 kv = *(const short8*)(xk2k + base);
      short8 vv = *(const short8*)(xk2v + base);
      float k[8]; float nrm = 0.f;
#pragma unroll
      for (int c = 0; c < 8; ++c) { k[c] = bf2f((unsigned short)kv[c]); nrm = fmaf(k[c], k[c], nrm); }
      const float inv = 1.0f / fmaxf(sqrtf(nrm), 1e-12f);
      f32x4 a0, a1, b0, b1;
#pragma unroll
      for (int c = 0; c < 4; ++c) { a0[c] = k[c] * inv; a1[c] = k[c + 4] * inv; }
#pragma unroll
      for (int c = 0; c < 4; ++c) { b0[c] = bf2f((unsigned short)vv[c]); b1[c] = bf2f((unsigned short)vv[c + 4]); }
      kn4[i][0] = a0; kn4[i][1] = a1;
      vv4[i][0] = b0; vv4[i][1] = b1;
    }
    __syncthreads();
    if (i >= 160) return;

    const float scale = expf(fminf(lrs[head], 4.6051702f));
    const f32x4 q0 = kn4[i][0], q1 = kn4[i][1];
    float den = 0.f;
    f32x4 acc0 = {0.f, 0.f, 0.f, 0.f}, acc1 = {0.f, 0.f, 0.f, 0.f};
    for (int j = 0; j < 160; ++j) {
      const float d = dot8(q0, q1, kn4[j][0], kn4[j][1]);
      const float p = __expf(fmaf(d, scale, -scale));
      den += p;
      acc0 += vv4[j][0] * p;
      acc1 += vv4[j][1] * p;
    }
    const float rden = 1.0f / den;
    short8 o;
#pragma unroll
    for (int c = 0; c < 4; ++c) { o[c] = (short)f2bf(acc0[c] * rden); o[c + 4] = (short)f2bf(acc1[c] * rden); }
    *(short8*)(vrow + ((((size_t)b * 8 + head) * 160 + h) * 160 + i) * 8) = o;
  }
}

// ================= axial column pass: block = (b, head, 4-col group), 640 threads =================
__global__ __launch_bounds__(640)
void col_attn_kernel(const unsigned short* __restrict__ xk2k, const float* __restrict__ lrs,
                     const unsigned short* __restrict__ vrow, unsigned short* __restrict__ ypad) {
  __shared__ f32x4 knT[4][161][2];
  __shared__ f32x4 vvT[4][161][2];
  int blk = blockIdx.x;
  const int wg = blk % 40; blk /= 40;
  const int head = blk % 8;
  const int b = blk / 8;
  const int w0 = wg * 4;
  const int t = threadIdx.x;

  {
    const int h = t >> 2, wc = t & 3;
    const size_t base = ((((size_t)b * 8 + head) * 160 + h) * 160 + (w0 + wc)) * 8;
    short8 kv = *(const short8*)(xk2k + base);
    short8 vv = *(const short8*)(vrow + base);
    float k[8]; float nrm = 0.f;
#pragma unroll
    for (int c = 0; c < 8; ++c) { k[c] = bf2f((unsigned short)kv[c]); nrm = fmaf(k[c], k[c], nrm); }
    const float inv = 1.0f / fmaxf(sqrtf(nrm), 1e-12f);
    f32x4 a0, a1, b0, b1;
#pragma unroll
    for (int c = 0; c < 4; ++c) { a0[c] = k[c] * inv; a1[c] = k[c + 4] * inv; }
#pragma unroll
    for (int c = 0; c < 4; ++c) { b0[c] = bf2f((unsigned short)vv[c]); b1[c] = bf2f((unsigned short)vv[c + 4]); }
    knT[wc][h][0] = a0; knT[wc][h][1] = a1;
    vvT[wc][h][0] = b0; vvT[wc][h][1] = b1;
  }
  __syncthreads();

  const int wi = t / 160, i = t % 160;
  const float scale = expf(fminf(lrs[head], 4.6051702f));
  const f32x4 q0 = knT[wi][i][0], q1 = knT[wi][i][1];
  float den = 0.f;
  f32x4 acc0 = {0.f, 0.f, 0.f, 0.f}, acc1 = {0.f, 0.f, 0.f, 0.f};
  for (int j = 0; j < 160; ++j) {
    const float d = dot8(q0, q1, knT[wi][j][0], knT[wi][j][1]);
    const float p = __expf(fmaf(d, scale, -scale));
    den += p;
    acc0 += vvT[wi][j][0] * p;
    acc1 += vvT[wi][j][1] * p;
  }
  const float rden = 1.0f / den;
  short8 o;
#pragma unroll
  for (int c = 0; c < 4; ++c) { o[c] = (short)f2bf(acc0[c] * rden); o[c + 4] = (short)f2bf(acc1[c] * rden); }
  *(short8*)(ypad + (((size_t)b * HPR + i + 1) * HPW + w0 + wi + 1) * 192 + 128 + head * 8) = o;
}

extern "C" void kernel_launch(void* const* d_in, const int* in_sizes, int n_in,
                              void* d_out, int out_size, void* d_ws, size_t ws_size,
                              hipStream_t stream) {
  const float* x     = (const float*)d_in[0];
  const float* w_in  = (const float*)d_in[1];
  const float* b_in  = (const float*)d_in[2];
  const float* w_out = (const float*)d_in[3];
  const float* b_out = (const float*)d_in[4];
  const float* ls    = (const float*)d_in[5];
  const float* lrs   = (const float*)d_in[6];
  const float* cw1   = (const float*)d_in[7];
  const float* cb1   = (const float*)d_in[8];
  const float* cw2   = (const float*)d_in[9];
  float* out = (float*)d_out;

  // workspace layout
  char* p = (char*)d_ws;
  unsigned short* xpad = (unsigned short*)p;  p += (size_t)Bc * HPR * HPW * 192 * 2;   // 20.4 MB
  unsigned short* ypad = (unsigned short*)p;  p += (size_t)Bc * HPR * HPW * 192 * 2;   // 20.4 MB
  unsigned short* xq   = (unsigned short*)p;  p += (size_t)Bc * Hc * Wc * 256 * 2;     // 26.2 MB
  unsigned short* xk2k = (unsigned short*)p;  p += (size_t)Bc * 8 * Hc * Wc * 8 * 2;   //  6.6 MB
  unsigned short* xk2v = (unsigned short*)p;  p += (size_t)Bc * 8 * Hc * Wc * 8 * 2;   //  6.6 MB
  unsigned short* vrow = (unsigned short*)p;  p += (size_t)Bc * 8 * Hc * Wc * 8 * 2;   //  6.6 MB
  unsigned short* wtr1 = (unsigned short*)p;  p += (size_t)9 * 384 * 192 * 2;          //  1.3 MB
  unsigned short* wtr2 = (unsigned short*)p;  p += (size_t)9 * 192 * 192 * 2;          //  0.7 MB
  float* biasf = (float*)p;

  // 1) fused prep
  prep_kernel<<<2476, 256, 0, stream>>>(x, xpad, ypad, w_in, wtr1, w_out, wtr2, cw1, cb1, cw2, biasf);
  // 2) conv_in 192->384: 8 waves (4hr x 2 co-halves), CT=2, grid (80, 6, 2)
  conv_mfma<384, 2, 2, 0><<<dim3(80, 6, Bc), 512, 0, stream>>>(xpad, wtr1, b_in, xq, xk2k, xk2v, nullptr);
  // 3) window attn (both variants) + axial row pass
  attn1_kernel<<<4096 + Bc * 160 * 8, 256, 0, stream>>>(xq, biasf, ls, lrs, xk2k, xk2v, ypad, vrow);
  // 4) axial column pass
  col_attn_kernel<<<Bc * 8 * 40, 640, 0, stream>>>(xk2k, lrs, vrow, ypad);
  // 5) conv_out 192->192: 8 waves, CT=2, grid (80, 3, 2)
  conv_mfma<192, 2, 2, 1><<<dim3(80, 3, Bc), 512, 0, stream>>>(ypad, wtr2, b_out, nullptr, nullptr, nullptr, out);
}

// Round 17
// 234.384 us; speedup vs baseline: 1.1794x; 1.0528x over previous
//
#include <hip/hip_runtime.h>
#include <math.h>

// GeoAB: conv3x3(192->384, bf16 MFMA, counted-vmcnt pipeline) -> [win+row attn | col attn]
//        -> conv3x3(192->192, CT=2).  B=2, H=W=160, WS=5, NH=8, CPH=8.
// R17 = R14 anchor (best measured 235.6us) + float4 prep loads.

typedef __attribute__((ext_vector_type(8))) short short8;
typedef __attribute__((ext_vector_type(4))) short short4v;
typedef __attribute__((ext_vector_type(4))) float f32x4;

constexpr int Hc = 160, Wc = 160, Bc = 2;
constexpr int HPR = 162;   // padded rows
constexpr int HPW = 164;   // padded cols

__device__ inline unsigned short f2bf(float f) {
  union { float f; unsigned u; } v; v.f = f;
  unsigned r = v.u + 0x7FFF + ((v.u >> 16) & 1);
  return (unsigned short)(r >> 16);
}
__device__ inline float bf2f(unsigned short h) {
  union { unsigned u; float f; } v; v.u = ((unsigned)h) << 16;
  return v.f;
}

__device__ inline void gl16(const void* g, void* l) {
  __builtin_amdgcn_global_load_lds((const __attribute__((address_space(1))) unsigned int*)g,
                                   (__attribute__((address_space(3))) unsigned int*)l, 16, 0, 0);
}

__device__ inline float dot8(f32x4 a0, f32x4 a1, f32x4 b0, f32x4 b1) {
  float d = a0[0] * b0[0];
  d = fmaf(a0[1], b0[1], d); d = fmaf(a0[2], b0[2], d); d = fmaf(a0[3], b0[3], d);
  d = fmaf(a1[0], b1[0], d); d = fmaf(a1[1], b1[1], d);
  d = fmaf(a1[2], b1[2], d); d = fmaf(a1[3], b1[3], d);
  return d;
}

// ================= fused prep: nchw->nhwc pad | borders | wxform x2 | cpb =================
// frag layout for weights: wtr[(((tap*6+cs)*NT + cotile)*64 + kh*16 + cor)*8 + j]
__global__ __launch_bounds__(256)
void prep_kernel(const float* __restrict__ x, unsigned short* __restrict__ xpad,
                 unsigned short* __restrict__ ypad,
                 const float* __restrict__ w_in, unsigned short* __restrict__ wtr1,
                 const float* __restrict__ w_out, unsigned short* __restrict__ wtr2,
                 const float* __restrict__ cw1, const float* __restrict__ cb1,
                 const float* __restrict__ cw2, float* __restrict__ biasf) {
  __shared__ float tile[192][33];
  const int bid = blockIdx.x;
  const int t = threadIdx.x;
  if (bid < 1600) {
    int blk = bid;
    const int w0 = (blk % 5) * 32; blk /= 5;
    const int h = blk % 160;
    const int b = blk / 160;
    // float4 loads: thread -> (c, 4w)
    for (int i = t; i < 192 * 8; i += 256) {
      int c = i >> 3, wq = i & 7;
      f32x4 v = *(const f32x4*)(x + (((size_t)b * 192 + c) * 160 + h) * 160 + w0 + wq * 4);
      tile[c][wq * 4 + 0] = v[0];
      tile[c][wq * 4 + 1] = v[1];
      tile[c][wq * 4 + 2] = v[2];
      tile[c][wq * 4 + 3] = v[3];
    }
    __syncthreads();
    for (int i = t; i < 32 * 24; i += 256) {
      int w = i / 24, c8 = i % 24;
      short8 o;
#pragma unroll
      for (int k = 0; k < 8; ++k) o[k] = (short)f2bf(tile[c8 * 8 + k][w]);
      *(short8*)(xpad + (((size_t)b * HPR + h + 1) * HPW + w0 + w + 1) * 192 + c8 * 8) = o;
    }
  } else if (bid < 1963) {
    const int NPOS = 968;
    const int total = 2 * 2 * NPOS * 24;
    int idx = (bid - 1600) * 256 + t;
    if (idx >= total) return;
    const int ch = idx % 24; int q = idx / 24;
    const int pos = q % NPOS; q /= NPOS;
    const int b = q & 1; const int buf = q >> 1;
    int row, col;
    if (pos < 328) { row = (pos < 164) ? 0 : 161; col = pos % 164; }
    else { int r = pos - 328; row = 1 + (r >> 2); int cm = r & 3; col = cm == 0 ? 0 : 160 + cm; }
    unsigned short* p = (buf ? ypad : xpad) + (((size_t)b * HPR + row) * HPW + col) * 192 + ch * 8;
    short8 z = {};
    *(short8*)p = z;
  } else if (bid < 2395) {
    const bool first = bid < 2251;
    const int CO = first ? 384 : 192;
    const int NT = CO / 16;
    const float* w = first ? w_in : w_out;
    unsigned short* wtr = first ? wtr1 : wtr2;
    int id = (bid - (first ? 1963 : 2251)) * 256 + t;
    if (id >= CO * 192) return;
    const int co = id / 192, ci = id % 192;
    const int cs = ci >> 5, kh = (ci >> 3) & 3, j = ci & 7;
    const int cotile = co >> 4, cor = co & 15;
    const float* wp = w + (size_t)id * 9;
#pragma unroll
    for (int tap = 0; tap < 9; ++tap)
      wtr[((((size_t)tap * 6 + cs) * NT + cotile) * 64 + kh * 16 + cor) * 8 + j] = f2bf(wp[tap]);
  } else {
    if (t >= 64) return;
    const int e = bid - 2395;
    const int d0 = e / 9, d1 = e % 9;
    const int r0 = d0 - 4, r1 = d1 - 4;
    float t0 = log2f(fabsf((float)r0) * 2.0f + 1.0f) * (1.0f / 3.0f); if (r0 < 0) t0 = -t0;
    float t1 = log2f(fabsf((float)r1) * 2.0f + 1.0f) * (1.0f / 3.0f); if (r1 < 0) t1 = -t1;
    const int lane = t;
    float acc[8];
#pragma unroll
    for (int n = 0; n < 8; ++n) acc[n] = 0.f;
    for (int k = lane; k < 512; k += 64) {
      float hk = fmaf(t0, cw1[k * 2 + 0], fmaf(t1, cw1[k * 2 + 1], cb1[k]));
      hk = fmaxf(hk, 0.f);
#pragma unroll
      for (int n = 0; n < 8; ++n) acc[n] = fmaf(hk, cw2[n * 512 + k], acc[n]);
    }
#pragma unroll
    for (int n = 0; n < 8; ++n) {
#pragma unroll
      for (int off = 32; off > 0; off >>= 1) acc[n] += __shfl_xor(acc[n], off, 64);
    }
    if (lane == 0) {
#pragma unroll
      for (int n = 0; n < 8; ++n)
        biasf[e * 8 + n] = 16.0f / (1.0f + expf(-acc[n]));
    }
  }
}

// ================= conv3x3 SAME, implicit GEMM, counted-vmcnt pipeline =================
// Block: 4 waves, one h-row each; wave tile 80w x (CT*16)co (acc 5xCT). BH=4, slab R=6, dbuf.
// Per cs: stage(next) -> [GROUP(Ak); LOADA(Ak,next)] x3 -> vmcnt(9*CT)+barrier.
// OUTMODE 0 (CT=4): cog 0..3 -> xq NHWC [b][h][w][256]; cog 4 -> xk2k; cog 5 -> xk2v.
// OUTMODE 1: fp32 NCHW store.
template<int COUT, int CT, int OUTMODE>
__global__ __launch_bounds__(256, 2)
void conv_mfma(const unsigned short* __restrict__ xin, const unsigned short* __restrict__ wtrA,
               const float* __restrict__ bias, unsigned short* __restrict__ obf,
               unsigned short* __restrict__ xk2k, unsigned short* __restrict__ xk2v,
               float* __restrict__ of32) {
  constexpr int CIN = 192;
  constexpr int R = 6;
  constexpr int TOTAL = R * 84 * 4;          // 2016 16B chunks per slab
  constexpr int SLAB = R * 84 * 32;          // shorts per buffer
  constexpr int NT = COUT / 16;
  __shared__ unsigned short slab[2 * SLAB];
  const int t = threadIdx.x, lane = t & 63, wid = t >> 6;
  const int bx = blockIdx.x, cog = blockIdx.y, b = blockIdx.z;
  const int ws = bx & 1, hb = bx >> 1;
  const int w0 = ws * 80, h0 = hb * 4;
  const int hr = wid;
  const int l15 = lane & 15, l4 = lane >> 4;
  const int co0 = cog * (CT * 16);

  f32x4 acc[5][CT];
#pragma unroll
  for (int ct = 0; ct < CT; ++ct) {
    f32x4 bi;
#pragma unroll
    for (int r = 0; r < 4; ++r) bi[r] = bias[co0 + ct * 16 + l4 * 4 + r];
#pragma unroll
    for (int mt = 0; mt < 5; ++mt) acc[mt][ct] = bi;
  }

  auto stage = [&](int cs, int bufbase) {
#pragma unroll
    for (int ib0 = 0; ib0 < 8; ++ib0) {
      const int ib = ib0 * 4 + wid;
      const int n = ib * 64 + lane;
      if (n < TOTAL) {
        const int c = n & 3, q = n >> 2;
        const int r = q / 84, wv = q - r * 84;
        const int csrc = c ^ ((wv >> 1) & 3);
        const unsigned short* g = xin +
            (((size_t)b * HPR + h0 + r) * HPW + w0 + wv) * CIN + cs * 32 + csrc * 8;
        gl16(g, &slab[bufbase + ib * 512]);
      }
    }
  };

#define BARRIER_CNT                                                              \
  {                                                                              \
    if constexpr (CT == 4)                                                       \
      asm volatile("s_waitcnt vmcnt(36)\n\ts_barrier" ::: "memory");             \
    else                                                                         \
      asm volatile("s_waitcnt vmcnt(18)\n\ts_barrier" ::: "memory");             \
  }

// load 3*CT A-frags (one ky group) into register array a
#define LOADA(a, ky, cs)                                                         \
  {                                                                              \
    _Pragma("unroll")                                                            \
    for (int kx = 0; kx < 3; ++kx) {                                             \
      _Pragma("unroll")                                                          \
      for (int ct = 0; ct < CT; ++ct)                                            \
        a[kx * CT + ct] = *(const short8*)(wtrA +                                \
            ((size_t)(((ky) * 3 + kx) * 6 + (cs)) * NT + cog * CT + ct) * 512 +  \
            lane * 8);                                                           \
    }                                                                            \
  }

// 15*CT MFMAs of one ky group against slab buffer at bufbase
#define GROUP(a, ky, bufbase)                                                    \
  {                                                                              \
    const unsigned short* srow = &slab[(bufbase) + (hr + (ky)) * 84 * 32];       \
    _Pragma("unroll")                                                            \
    for (int kx = 0; kx < 3; ++kx) {                                             \
      _Pragma("unroll")                                                          \
      for (int mt = 0; mt < 5; ++mt) {                                           \
        const int wv = mt * 16 + l15 + kx;                                       \
        const int cr = l4 ^ ((wv >> 1) & 3);                                     \
        short8 bf = *(const short8*)(srow + wv * 32 + cr * 8);                   \
        _Pragma("unroll")                                                        \
        for (int ct = 0; ct < CT; ++ct)                                          \
          acc[mt][ct] =                                                          \
              __builtin_amdgcn_mfma_f32_16x16x32_bf16(a[kx * CT + ct], bf,       \
                                                      acc[mt][ct], 0, 0, 0);     \
      }                                                                          \
    }                                                                            \
  }

// one cs step; A0f/A1f/A2f hold cs's fragments on entry, cs+1's on exit
#define CSBODY(cs, base, nbase, LAST)                                            \
  {                                                                              \
    if (!(LAST)) stage((cs) + 1, nbase);                                         \
    __builtin_amdgcn_s_setprio(1);                                               \
    GROUP(A0f, 0, base);                                                         \
    __builtin_amdgcn_s_setprio(0);                                               \
    if (!(LAST)) LOADA(A0f, 0, (cs) + 1);                                        \
    __builtin_amdgcn_s_setprio(1);                                               \
    GROUP(A1f, 1, base);                                                         \
    __builtin_amdgcn_s_setprio(0);                                               \
    if (!(LAST)) LOADA(A1f, 1, (cs) + 1);                                        \
    __builtin_amdgcn_s_setprio(1);                                               \
    GROUP(A2f, 2, base);                                                         \
    __builtin_amdgcn_s_setprio(0);                                               \
    if (!(LAST)) {                                                               \
      LOADA(A2f, 2, (cs) + 1);                                                   \
      BARRIER_CNT;                                                               \
    }                                                                            \
  }

  short8 A0f[3 * CT], A1f[3 * CT], A2f[3 * CT];
  stage(0, 0);
  LOADA(A0f, 0, 0);
  LOADA(A1f, 1, 0);
  LOADA(A2f, 2, 0);
  BARRIER_CNT;

  CSBODY(0, 0, SLAB, 0);
  CSBODY(1, SLAB, 0, 0);
  CSBODY(2, 0, SLAB, 0);
  CSBODY(3, SLAB, 0, 0);
  CSBODY(4, 0, SLAB, 0);
  CSBODY(5, SLAB, 0, 1);
#undef LOADA
#undef GROUP
#undef CSBODY
#undef BARRIER_CNT

  // ---- epilogue: D row = co (l4*4+r), col = w (l15) ----
  const int h = h0 + hr;
  if (OUTMODE == 0) {
    if (co0 < 256) {
#pragma unroll
      for (int mt = 0; mt < 5; ++mt) {
        const int w = w0 + mt * 16 + l15;
        unsigned short* dst0 = obf + (((size_t)b * Hc + h) * Wc + w) * 256 + co0 + l4 * 4;
#pragma unroll
        for (int ct = 0; ct < CT; ++ct) {
          short4v s;
#pragma unroll
          for (int r = 0; r < 4; ++r) s[r] = (short)f2bf(acc[mt][ct][r]);
          *(short4v*)(dst0 + ct * 16) = s;
        }
      }
    } else {
      unsigned short* xk2 = (co0 == 256) ? xk2k : xk2v;
#pragma unroll
      for (int mt = 0; mt < 5; ++mt) {
        const int w = w0 + mt * 16 + l15;
#pragma unroll
        for (int ct = 0; ct < CT; ++ct) {
          const int rel = ct * 16 + l4 * 4;
          const int head = rel >> 3, within = rel & 7;
          short4v s;
#pragma unroll
          for (int r = 0; r < 4; ++r) s[r] = (short)f2bf(acc[mt][ct][r]);
          *(short4v*)(xk2 + ((((size_t)b * 8 + head) * 160 + h) * 160 + w) * 8 + within) = s;
        }
      }
    }
  } else {
#pragma unroll
    for (int mt = 0; mt < 5; ++mt) {
      const int w = w0 + mt * 16 + l15;
#pragma unroll
      for (int ct = 0; ct < CT; ++ct)
#pragma unroll
        for (int r = 0; r < 4; ++r) {
          const int co = co0 + ct * 16 + l4 * 4 + r;
          of32[(((size_t)b * COUT + co) * Hc + h) * Wc + w] = acc[mt][ct][r];
        }
    }
  }
}

// ================= fused attn pass 1: window attn (both variants) + axial row pass =================
__global__ __launch_bounds__(256)
void attn1_kernel(const unsigned short* __restrict__ xq, const float* __restrict__ biasf,
                  const float* __restrict__ logit_scale, const float* __restrict__ lrs,
                  const unsigned short* __restrict__ xk2k, const unsigned short* __restrict__ xk2v,
                  unsigned short* __restrict__ ypad, unsigned short* __restrict__ vrow) {
  const int bid = blockIdx.x;
  if (bid < 4096) {
    // ---- 5x5 window cosine attention ----
    __shared__ f32x4 kn4[8][25][2];
    __shared__ f32x4 vv4[8][25][2];
    const int t = threadIdx.x;
    const int head = t & 7;
    const int i = t >> 3;           // 0..31, active < 25
    const int b = bid >> 11;
    const int r = bid & 2047;
    const int variant = r >> 10;
    const int blk = r & 1023;
    const int chan_off = variant ? 128 : 0;
    const int y_ch_off = variant ? 64 : 0;
    const int shift_in = variant ? 3 : 0;
    const int shift_out = variant ? 2 : 0;
    const int wb_i = blk % 32, hb_i = blk / 32;
    const int wi = i / 5, wj = i % 5;
    const int gh = hb_i * 5 + wi, gw = wb_i * 5 + wj;
    const int sh = (gh + shift_in) % Hc, sw = (gw + shift_in) % Wc;

    if (i < 25) {
      const unsigned short* base = xq + (((size_t)b * Hc + sh) * Wc + sw) * 256 + chan_off + head * 8;
      short8 kv = *(const short8*)base;
      short8 vv = *(const short8*)(base + 64);
      float k[8]; float nrm = 0.f;
#pragma unroll
      for (int c = 0; c < 8; ++c) { k[c] = bf2f((unsigned short)kv[c]); nrm = fmaf(k[c], k[c], nrm); }
      const float inv = 1.0f / fmaxf(sqrtf(nrm), 1e-12f);
      f32x4 a0, a1, b0, b1;
#pragma unroll
      for (int c = 0; c < 4; ++c) { a0[c] = k[c] * inv; a1[c] = k[c + 4] * inv; }
#pragma unroll
      for (int c = 0; c < 4; ++c) { b0[c] = bf2f((unsigned short)vv[c]); b1[c] = bf2f((unsigned short)vv[c + 4]); }
      kn4[head][i][0] = a0; kn4[head][i][1] = a1;
      vv4[head][i][0] = b0; vv4[head][i][1] = b1;
    }
    __syncthreads();
    if (i >= 25) return;

    const float scale = expf(fminf(logit_scale[head], 4.6051702f));
    const f32x4 q0 = kn4[head][i][0], q1 = kn4[head][i][1];
    float s[25];
#pragma unroll
    for (int j = 0; j < 25; ++j) {
      const float d = dot8(q0, q1, kn4[head][j][0], kn4[head][j][1]);
      const int d0 = wi - (j / 5) + 4, d1 = wj - (j % 5) + 4;
      s[j] = fmaf(d, scale, biasf[(d0 * 9 + d1) * 8 + head]);
    }
    float m = -1e30f;
#pragma unroll
    for (int j = 0; j < 25; ++j) m = fmaxf(m, s[j]);
    float den = 0.f;
    f32x4 acc0 = {0.f, 0.f, 0.f, 0.f}, acc1 = {0.f, 0.f, 0.f, 0.f};
#pragma unroll
    for (int j = 0; j < 25; ++j) {
      const float p = __expf(s[j] - m);
      den += p;
      acc0 += vv4[head][j][0] * p;
      acc1 += vv4[head][j][1] * p;
    }
    const float rden = 1.0f / den;
    const int oh = (gh + shift_out) % Hc, ow = (gw + shift_out) % Wc;
    short8 o;
#pragma unroll
    for (int c = 0; c < 4; ++c) { o[c] = (short)f2bf(acc0[c] * rden); o[c + 4] = (short)f2bf(acc1[c] * rden); }
    *(short8*)(ypad + (((size_t)b * HPR + oh + 1) * HPW + ow + 1) * 192 + y_ch_off + head * 8) = o;
  } else {
    // ---- axial row pass -> vrow bf16 [b][head][h][w][8] ----
    __shared__ f32x4 kn4[160][2];
    __shared__ f32x4 vv4[160][2];
    int u = bid - 4096;
    const int head = u % 8; u /= 8;
    const int h = u % 160;
    const int b = u / 160;
    const int i = threadIdx.x;

    if (i < 160) {
      const size_t base = ((((size_t)b * 8 + head) * 160 + h) * 160 + i) * 8;
      short8 kv = *(const short8*)(xk2k + base);
      short8 vv = *(const short8*)(xk2v + base);
      float k[8]; float nrm = 0.f;
#pragma unroll
      for (int c = 0; c < 8; ++c) { k[c] = bf2f((unsigned short)kv[c]); nrm = fmaf(k[c], k[c], nrm); }
      const float inv = 1.0f / fmaxf(sqrtf(nrm), 1e-12f);
      f32x4 a0, a1, b0, b1;
#pragma unroll
      for (int c = 0; c < 4; ++c) { a0[c] = k[c] * inv; a1[c] = k[c + 4] * inv; }
#pragma unroll
      for (int c = 0; c < 4; ++c) { b0[c] = bf2f((unsigned short)vv[c]); b1[c] = bf2f((unsigned short)vv[c + 4]); }
      kn4[i][0] = a0; kn4[i][1] = a1;
      vv4[i][0] = b0; vv4[i][1] = b1;
    }
    __syncthreads();
    if (i >= 160) return;

    const float scale = expf(fminf(lrs[head], 4.6051702f));
    const f32x4 q0 = kn4[i][0], q1 = kn4[i][1];
    float den = 0.f;
    f32x4 acc0 = {0.f, 0.f, 0.f, 0.f}, acc1 = {0.f, 0.f, 0.f, 0.f};
    for (int j = 0; j < 160; ++j) {
      const float d = dot8(q0, q1, kn4[j][0], kn4[j][1]);
      const float p = __expf(fmaf(d, scale, -scale));
      den += p;
      acc0 += vv4[j][0] * p;
      acc1 += vv4[j][1] * p;
    }
    const float rden = 1.0f / den;
    short8 o;
#pragma unroll
    for (int c = 0; c < 4; ++c) { o[c] = (short)f2bf(acc0[c] * rden); o[c + 4] = (short)f2bf(acc1[c] * rden); }
    *(short8*)(vrow + ((((size_t)b * 8 + head) * 160 + h) * 160 + i) * 8) = o;
  }
}

// ================= axial column pass: block = (b, head, 4-col group), 640 threads =================
__global__ __launch_bounds__(640)
void col_attn_kernel(const unsigned short* __restrict__ xk2k, const float* __restrict__ lrs,
                     const unsigned short* __restrict__ vrow, unsigned short* __restrict__ ypad) {
  __shared__ f32x4 knT[4][161][2];
  __shared__ f32x4 vvT[4][161][2];
  int blk = blockIdx.x;
  const int wg = blk % 40; blk /= 40;
  const int head = blk % 8;
  const int b = blk / 8;
  const int w0 = wg * 4;
  const int t = threadIdx.x;

  {
    const int h = t >> 2, wc = t & 3;
    const size_t base = ((((size_t)b * 8 + head) * 160 + h) * 160 + (w0 + wc)) * 8;
    short8 kv = *(const short8*)(xk2k + base);
    short8 vv = *(const short8*)(vrow + base);
    float k[8]; float nrm = 0.f;
#pragma unroll
    for (int c = 0; c < 8; ++c) { k[c] = bf2f((unsigned short)kv[c]); nrm = fmaf(k[c], k[c], nrm); }
    const float inv = 1.0f / fmaxf(sqrtf(nrm), 1e-12f);
    f32x4 a0, a1, b0, b1;
#pragma unroll
    for (int c = 0; c < 4; ++c) { a0[c] = k[c] * inv; a1[c] = k[c + 4] * inv; }
#pragma unroll
    for (int c = 0; c < 4; ++c) { b0[c] = bf2f((unsigned short)vv[c]); b1[c] = bf2f((unsigned short)vv[c + 4]); }
    knT[wc][h][0] = a0; knT[wc][h][1] = a1;
    vvT[wc][h][0] = b0; vvT[wc][h][1] = b1;
  }
  __syncthreads();

  const int wi = t / 160, i = t % 160;
  const float scale = expf(fminf(lrs[head], 4.6051702f));
  const f32x4 q0 = knT[wi][i][0], q1 = knT[wi][i][1];
  float den = 0.f;
  f32x4 acc0 = {0.f, 0.f, 0.f, 0.f}, acc1 = {0.f, 0.f, 0.f, 0.f};
  for (int j = 0; j < 160; ++j) {
    const float d = dot8(q0, q1, knT[wi][j][0], knT[wi][j][1]);
    const float p = __expf(fmaf(d, scale, -scale));
    den += p;
    acc0 += vvT[wi][j][0] * p;
    acc1 += vvT[wi][j][1] * p;
  }
  const float rden = 1.0f / den;
  short8 o;
#pragma unroll
  for (int c = 0; c < 4; ++c) { o[c] = (short)f2bf(acc0[c] * rden); o[c + 4] = (short)f2bf(acc1[c] * rden); }
  *(short8*)(ypad + (((size_t)b * HPR + i + 1) * HPW + w0 + wi + 1) * 192 + 128 + head * 8) = o;
}

extern "C" void kernel_launch(void* const* d_in, const int* in_sizes, int n_in,
                              void* d_out, int out_size, void* d_ws, size_t ws_size,
                              hipStream_t stream) {
  const float* x     = (const float*)d_in[0];
  const float* w_in  = (const float*)d_in[1];
  const float* b_in  = (const float*)d_in[2];
  const float* w_out = (const float*)d_in[3];
  const float* b_out = (const float*)d_in[4];
  const float* ls    = (const float*)d_in[5];
  const float* lrs   = (const float*)d_in[6];
  const float* cw1   = (const float*)d_in[7];
  const float* cb1   = (const float*)d_in[8];
  const float* cw2   = (const float*)d_in[9];
  float* out = (float*)d_out;

  // workspace layout
  char* p = (char*)d_ws;
  unsigned short* xpad = (unsigned short*)p;  p += (size_t)Bc * HPR * HPW * 192 * 2;   // 20.4 MB
  unsigned short* ypad = (unsigned short*)p;  p += (size_t)Bc * HPR * HPW * 192 * 2;   // 20.4 MB
  unsigned short* xq   = (unsigned short*)p;  p += (size_t)Bc * Hc * Wc * 256 * 2;     // 26.2 MB
  unsigned short* xk2k = (unsigned short*)p;  p += (size_t)Bc * 8 * Hc * Wc * 8 * 2;   //  6.6 MB
  unsigned short* xk2v = (unsigned short*)p;  p += (size_t)Bc * 8 * Hc * Wc * 8 * 2;   //  6.6 MB
  unsigned short* vrow = (unsigned short*)p;  p += (size_t)Bc * 8 * Hc * Wc * 8 * 2;   //  6.6 MB
  unsigned short* wtr1 = (unsigned short*)p;  p += (size_t)9 * 384 * 192 * 2;          //  1.3 MB
  unsigned short* wtr2 = (unsigned short*)p;  p += (size_t)9 * 192 * 192 * 2;          //  0.7 MB
  float* biasf = (float*)p;

  // 1) fused prep
  prep_kernel<<<2476, 256, 0, stream>>>(x, xpad, ypad, w_in, wtr1, w_out, wtr2, cw1, cb1, cw2, biasf);
  // 2) conv_in 192->384, CT=4 (xq + xk2k/xk2v epilogue), 960 blocks
  conv_mfma<384, 4, 0><<<dim3(80, 6, Bc), 256, 0, stream>>>(xpad, wtr1, b_in, xq, xk2k, xk2v, nullptr);
  // 3) window attn (both variants) + axial row pass
  attn1_kernel<<<4096 + Bc * 160 * 8, 256, 0, stream>>>(xq, biasf, ls, lrs, xk2k, xk2v, ypad, vrow);
  // 4) axial column pass
  col_attn_kernel<<<Bc * 8 * 40, 640, 0, stream>>>(xk2k, lrs, vrow, ypad);
  // 5) conv_out 192->192, CT=2, 960 blocks
  conv_mfma<192, 2, 1><<<dim3(80, 6, Bc), 256, 0, stream>>>(ypad, wtr2, b_out, nullptr, nullptr, nullptr, out);
}